// Round 1
// baseline (729.935 us; speedup 1.0000x reference)
//
#include <hip/hip_runtime.h>
#include <hip/hip_bf16.h>

#define THRES 1.0f
#define DECAY 0.9375f

// ---------------- sizes ----------------
// image (3,128,128) -> avgpool (3,64,64) = 12288
// conv1 out (32,60,60) = 115200 ; conv2 out (64,56,56) = 200704
// w_l1 (512,200704), w_l2 (10,512)
// ws layout (in floats):
#define OFF_SIN    0u              // 20*12288   = 245760
#define OFF_D1     245760u         // 20*115200  = 2304000
#define OFF_SC1    2549760u        // 20*115200  = 2304000
#define OFF_D2     4853760u        // 19*200704  = 3813376
#define OFF_MASK   8667136u        // 200704 (u32)
#define OFF_PART   8867840u        // 896*76     = 68096
#define OFF_Z      8935936u        // 512*19     = 9728
// total ~ 8.95M floats ~ 35.8 MB

// ---------------- input layer: avgpool + IF (no decay) ----------------
__global__ void k_input(const float* __restrict__ image, float* __restrict__ s_in) {
    int idx = blockIdx.x * 256 + threadIdx.x;
    if (idx >= 12288) return;
    int c = idx >> 12;            // /4096
    int p = idx & 4095;
    int y = p >> 6, x = p & 63;
    const float* b = image + c * 16384 + (2 * y) * 128 + 2 * x;
    float v = ((b[0] + b[1]) + (b[128] + b[129])) * 0.25f;
    float mp = 0.f;
    for (int t = 0; t < 20; ++t) {
        mp += v;
        float s = (mp >= THRES) ? 1.f : 0.f;
        s_in[t * 12288 + idx] = s;
        mp -= s;
    }
}

// ---------------- conv1 batched drive: D1[t] = conv(s_in[t], w_c1) ----------------
// tasks: t(20) x og(8) x y(60) x xc(6 chunks of 10)  = 57600
__global__ void k_conv1(const float* __restrict__ s_in, const float* __restrict__ w_c1,
                        float* __restrict__ D1) {
    int task = blockIdx.x * 256 + threadIdx.x;
    if (task >= 57600) return;
    int xc = task % 6;
    int tmp = task / 6;
    int y = tmp % 60; tmp /= 60;
    int og = tmp % 8;
    int t  = tmp / 8;
    int o0 = og * 4, x0 = xc * 10;
    float acc[4][10];
    #pragma unroll
    for (int o = 0; o < 4; ++o)
        #pragma unroll
        for (int x = 0; x < 10; ++x) acc[o][x] = 0.f;
    const float* inb = s_in + t * 12288;
    for (int c = 0; c < 3; ++c)
        for (int ky = 0; ky < 5; ++ky) {
            float in[14];
            const float* row = inb + c * 4096 + (y + ky) * 64 + x0;
            #pragma unroll
            for (int i = 0; i < 14; ++i) in[i] = row[i];
            #pragma unroll
            for (int kx = 0; kx < 5; ++kx)
                #pragma unroll
                for (int o = 0; o < 4; ++o) {
                    float w = w_c1[((o0 + o) * 3 + c) * 25 + ky * 5 + kx];
                    #pragma unroll
                    for (int x = 0; x < 10; ++x) acc[o][x] += in[x + kx] * w;
                }
        }
    #pragma unroll
    for (int o = 0; o < 4; ++o)
        #pragma unroll
        for (int x = 0; x < 10; ++x)
            D1[((t * 32 + o0 + o) * 60 + y) * 60 + x0 + x] = acc[o][x];
}

// ---------------- conv1 LIF chain -> s_c1 (float spikes) ----------------
__global__ void k_lif1(const float* __restrict__ D1, float* __restrict__ s_c1) {
    int idx = blockIdx.x * 256 + threadIdx.x;
    if (idx >= 115200) return;
    float mp = 0.f;
    for (int t = 0; t < 20; ++t) {
        mp += D1[t * 115200 + idx];
        float s = (mp >= THRES) ? 1.f : 0.f;
        s_c1[t * 115200 + idx] = s;
        mp = (s != 0.f) ? (mp - THRES) : mp * DECAY;
    }
}

// ---------------- conv2 batched drive: D2[tp] = conv(s_c1[tp], w_c2) (drive for step tp+1) ----
// tasks: tp(19) x og(16) x y(56) x xc(7 chunks of 8) = 119168
__global__ void k_conv2(const float* __restrict__ s_c1, const float* __restrict__ w_c2,
                        float* __restrict__ D2) {
    int task = blockIdx.x * 256 + threadIdx.x;
    if (task >= 119168) return;
    int xc = task % 7;
    int tmp = task / 7;
    int y = tmp % 56; tmp /= 56;
    int og = tmp % 16;
    int tp = tmp / 16;
    int o0 = og * 4, x0 = xc * 8;
    float acc[4][8];
    #pragma unroll
    for (int o = 0; o < 4; ++o)
        #pragma unroll
        for (int x = 0; x < 8; ++x) acc[o][x] = 0.f;
    const float* inb = s_c1 + tp * 115200;
    for (int c = 0; c < 32; ++c)
        #pragma unroll
        for (int ky = 0; ky < 5; ++ky) {
            float in[12];
            const float* row = inb + c * 3600 + (y + ky) * 60 + x0;
            #pragma unroll
            for (int i = 0; i < 12; ++i) in[i] = row[i];
            #pragma unroll
            for (int kx = 0; kx < 5; ++kx)
                #pragma unroll
                for (int o = 0; o < 4; ++o) {
                    float w = w_c2[((o0 + o) * 32 + c) * 25 + ky * 5 + kx];
                    #pragma unroll
                    for (int x = 0; x < 8; ++x) acc[o][x] += in[x + kx] * w;
                }
        }
    #pragma unroll
    for (int o = 0; o < 4; ++o)
        #pragma unroll
        for (int x = 0; x < 8; ++x)
            D2[((tp * 64 + o0 + o) * 56 + y) * 56 + x0 + x] = acc[o][x];
}

// ---------------- conv2 LIF chain -> packed spike masks (bit u = spike at step u) -----
__global__ void k_lif2(const float* __restrict__ D2, unsigned int* __restrict__ mask) {
    int idx = blockIdx.x * 256 + threadIdx.x;
    if (idx >= 200704) return;
    float mp = 0.f;
    unsigned int m = 0u;  // step 0 spike is always 0 (zero drive, zero mempot)
    for (int u = 1; u < 20; ++u) {
        mp += D2[(u - 1) * 200704 + idx];
        float s = (mp >= THRES) ? 1.f : 0.f;
        if (s != 0.f) m |= (1u << u);
        mp = (s != 0.f) ? (mp - THRES) : mp * DECAY;
    }
    mask[idx] = m;
}

// ---------------- linear1 GEMM: Z[i][k] = sum_j W[i][j] * spike(step k, j), k=0..18 ----
// grid: 128 rowgroups (4 rows each) x 7 j-splits (28672 each) = 896 blocks
__global__ void __launch_bounds__(256) k_gemm(const float* __restrict__ W,
                                              const unsigned int* __restrict__ mask,
                                              float* __restrict__ partials) {
    int rg = blockIdx.x / 7, js = blockIdx.x % 7;
    int i0 = rg * 4;
    size_t j0 = (size_t)js * 28672;
    int tid = threadIdx.x;
    float acc[4][19];
    #pragma unroll
    for (int r = 0; r < 4; ++r)
        #pragma unroll
        for (int t = 0; t < 19; ++t) acc[r][t] = 0.f;

    const float* W0 = W + (size_t)(i0 + 0) * 200704 + j0;
    const float* W1 = W + (size_t)(i0 + 1) * 200704 + j0;
    const float* W2 = W + (size_t)(i0 + 2) * 200704 + j0;
    const float* W3 = W + (size_t)(i0 + 3) * 200704 + j0;
    const unsigned int* M = mask + j0;

    for (int it = 0; it < 28; ++it) {
        int j = (it * 256 + tid) * 4;
        uint4  m4 = *(const uint4*)(M + j);
        float4 a0 = *(const float4*)(W0 + j);
        float4 a1 = *(const float4*)(W1 + j);
        float4 a2 = *(const float4*)(W2 + j);
        float4 a3 = *(const float4*)(W3 + j);
        unsigned int mm[4] = {m4.x, m4.y, m4.z, m4.w};
        float w0a[4] = {a0.x, a0.y, a0.z, a0.w};
        float w1a[4] = {a1.x, a1.y, a1.z, a1.w};
        float w2a[4] = {a2.x, a2.y, a2.z, a2.w};
        float w3a[4] = {a3.x, a3.y, a3.z, a3.w};
        #pragma unroll
        for (int jj = 0; jj < 4; ++jj) {
            unsigned int m = mm[jj];
            float v0 = w0a[jj], v1 = w1a[jj], v2 = w2a[jj], v3 = w3a[jj];
            #pragma unroll
            for (int t = 0; t < 19; ++t) {
                float s = (float)((m >> t) & 1u);
                acc[0][t] += v0 * s;
                acc[1][t] += v1 * s;
                acc[2][t] += v2 * s;
                acc[3][t] += v3 * s;
            }
        }
    }

    __shared__ float red[4][76];
    int wv = tid >> 6, ln = tid & 63;
    #pragma unroll
    for (int r = 0; r < 4; ++r)
        #pragma unroll
        for (int t = 0; t < 19; ++t) {
            float v = acc[r][t];
            v += __shfl_xor(v, 32);
            v += __shfl_xor(v, 16);
            v += __shfl_xor(v, 8);
            v += __shfl_xor(v, 4);
            v += __shfl_xor(v, 2);
            v += __shfl_xor(v, 1);
            if (ln == 0) red[wv][r * 19 + t] = v;
        }
    __syncthreads();
    if (tid < 76)
        partials[(size_t)blockIdx.x * 76 + tid] =
            red[0][tid] + red[1][tid] + red[2][tid] + red[3][tid];
}

// ---------------- reduce partials over 7 j-splits -> Z[512][19] ----------------
__global__ void k_reduce(const float* __restrict__ partials, float* __restrict__ Z) {
    int idx = blockIdx.x * 256 + threadIdx.x;
    if (idx >= 9728) return;
    int i = idx / 19, k = idx % 19;
    int rg = i >> 2, r = i & 3;
    float s = 0.f;
    for (int js = 0; js < 7; ++js)
        s += partials[(size_t)(rg * 7 + js) * 76 + r * 19 + k];
    Z[idx] = s;
}

// ---------------- head: linear1 LIF chain, linear2 matvec + LIF chain, output ----------
__global__ void k_head(const float* __restrict__ Z, const float* __restrict__ w_l2,
                       float* __restrict__ out) {
    __shared__ float sl1[20][512];
    __shared__ float d2[20][10];
    int tid = threadIdx.x;
    // linear1 LIF chain (each thread = one neuron)
    {
        float mp = 0.f;
        sl1[0][tid] = 0.f;   // step 0: zero drive -> no spike
        for (int u = 1; u < 20; ++u) {
            mp += Z[tid * 19 + (u - 1)];
            float s = (mp >= THRES) ? 1.f : 0.f;
            sl1[u][tid] = s;
            mp = (s != 0.f) ? (mp - THRES) : mp * DECAY;
        }
    }
    __syncthreads();
    // linear2 drives: d2[u][o] = w_l2[o] . sl1[u-1], u=1..19
    int wv = tid >> 6, ln = tid & 63;
    for (int task = wv; task < 190; task += 8) {
        int u = task / 10 + 1;
        int o = task % 10;
        float p = 0.f;
        for (int ii = ln; ii < 512; ii += 64) p += w_l2[o * 512 + ii] * sl1[u - 1][ii];
        p += __shfl_xor(p, 32);
        p += __shfl_xor(p, 16);
        p += __shfl_xor(p, 8);
        p += __shfl_xor(p, 4);
        p += __shfl_xor(p, 2);
        p += __shfl_xor(p, 1);
        if (ln == 0) d2[u][o] = p;
    }
    __syncthreads();
    // linear2 LIF chain + write output (21 rows x 10)
    if (tid < 10) {
        out[tid] = 0.f;        // row 0 (pre-scan zeros)
        out[10 + tid] = 0.f;   // row 1 (step 0: zero drive)
        float mp = 0.f;
        for (int u = 1; u < 20; ++u) {
            mp += d2[u][tid];
            float s = (mp >= THRES) ? 1.f : 0.f;
            out[(u + 1) * 10 + tid] = s;
            mp = (s != 0.f) ? (mp - THRES) : mp * DECAY;
        }
    }
}

extern "C" void kernel_launch(void* const* d_in, const int* in_sizes, int n_in,
                              void* d_out, int out_size, void* d_ws, size_t ws_size,
                              hipStream_t stream) {
    const float* image = (const float*)d_in[0];
    const float* w_c1  = (const float*)d_in[1];
    const float* w_c2  = (const float*)d_in[2];
    const float* w_l1  = (const float*)d_in[3];
    const float* w_l2  = (const float*)d_in[4];
    float* out = (float*)d_out;
    float* ws  = (float*)d_ws;

    float*        s_in  = ws + OFF_SIN;
    float*        D1    = ws + OFF_D1;
    float*        s_c1  = ws + OFF_SC1;
    float*        D2    = ws + OFF_D2;
    unsigned int* mask  = (unsigned int*)(ws + OFF_MASK);
    float*        part  = ws + OFF_PART;
    float*        Z     = ws + OFF_Z;

    k_input <<<48,  256, 0, stream>>>(image, s_in);
    k_conv1 <<<225, 256, 0, stream>>>(s_in, w_c1, D1);
    k_lif1  <<<450, 256, 0, stream>>>(D1, s_c1);
    k_conv2 <<<466, 256, 0, stream>>>(s_c1, w_c2, D2);
    k_lif2  <<<784, 256, 0, stream>>>(D2, mask);
    k_gemm  <<<896, 256, 0, stream>>>(w_l1, mask, part);
    k_reduce<<<38,  256, 0, stream>>>(part, Z);
    k_head  <<<1,   512, 0, stream>>>(Z, w_l2, out);
}